// Round 15
// baseline (304.115 us; speedup 1.0000x reference)
//
#include <hip/hip_runtime.h>
#include <hip/hip_bf16.h>

#define NN 1024
#define JT 128   // j-subtile rows per loop iteration (8 waves x 16)
#define LSTR 72  // bf16 row stride (2-way bank aliasing only — free)
#define EPSV 1e-5f
#define BIGINF 1e5f

typedef __attribute__((ext_vector_type(8))) short short8;
typedef __attribute__((ext_vector_type(4))) short short4v;
typedef __attribute__((ext_vector_type(4))) float f32x4;

__device__ __forceinline__ float siluf(float v) {
    return v * __builtin_amdgcn_rcpf(1.0f + __expf(-v));
}
__device__ __forceinline__ float pnorm(float dx, float dy, float dz) {
    return sqrtf(dx * dx + dy * dy + dz * dz + EPSV);
}
__device__ __forceinline__ float wsum(float v) {
#pragma unroll
    for (int off = 32; off > 0; off >>= 1) v += __shfl_xor(v, off, 64);
    return v;
}
__device__ __forceinline__ float red16(float v) {
    v += __shfl_xor(v, 1, 64); v += __shfl_xor(v, 2, 64);
    v += __shfl_xor(v, 4, 64); v += __shfl_xor(v, 8, 64);
    return v;
}
__device__ __forceinline__ float redquad(float v) {
    v += __shfl_xor(v, 16, 64); v += __shfl_xor(v, 32, 64);
    return v;
}
__device__ __forceinline__ short f2bs(float v) {  // RNE (weights, once)
    __hip_bfloat16 b = __float2bfloat16(v);
    return *reinterpret_cast<short*>(&b);
}
__device__ __forceinline__ short f2bt(float v) {  // truncate (hot path)
    return (short)(__float_as_uint(v) >> 16);
}

// ---- kA (fused): [0,NN): HA/HB/HBT; [NN,NN+64): weight transposes; NN+64: wsv/svb ----
__global__ void kA(const float* __restrict__ h, const float* __restrict__ ew1,
                   const float* __restrict__ eb1, const float* __restrict__ ew2,
                   const float* __restrict__ cw1, const float* __restrict__ fw1,
                   const float* __restrict__ fw2, const float* __restrict__ aw,
                   const float* __restrict__ ab, const float* __restrict__ eb2,
                   float* __restrict__ HA, float* __restrict__ HB,
                   float* __restrict__ HBT, short* __restrict__ ew2T,
                   short* __restrict__ cw1T, short* __restrict__ fw1T,
                   short* __restrict__ fw2T, float* __restrict__ wsv,
                   float* __restrict__ svb) {
    const int b = blockIdx.x;
    const int o = threadIdx.x;
    if (b < NN) {
        const int i = b;
        float hv = h[i * 64 + o];
        float a = 0.f, bb = eb1[o];
#pragma unroll
        for (int k = 0; k < 64; k++) {
            float hk = __shfl(hv, k, 64);
            a += hk * ew1[k * 64 + o];
            bb += hk * ew1[(64 + k) * 64 + o];
        }
        HA[i * 64 + o] = a;
        HB[i * 64 + o] = bb;
        HBT[o * NN + i] = bb;
    } else if (b < NN + 64) {
        const int r = b - NN;
        ew2T[r * 64 + o] = f2bs(ew2[o * 64 + r]);
        cw1T[r * 64 + o] = f2bs(cw1[o * 64 + r]);
        fw1T[r * 64 + o] = f2bs(fw1[o * 64 + r]);
        if (r < 32) fw2T[r * 64 + o] = f2bs(fw2[o * 32 + r]);
    } else {
        float s = 0.f;
#pragma unroll
        for (int q = 0; q < 64; q++) s += ew2[o * 64 + q] * aw[q];
        wsv[o] = s;
        float e = wsum(eb2[o] * aw[o]);
        if (o == 0) svb[0] = e + ab[0];
    }
}

// ---- kBn: pass 1 — thread t handles j=4t..4t+3, coalesced HBT float4 loads ----
__global__ __launch_bounds__(256) void kBn(
    const float* __restrict__ x, const float* __restrict__ ew1,
    const float* __restrict__ HA, const float* __restrict__ HBT,
    const float* __restrict__ wsv, const float* __restrict__ svb,
    const float* __restrict__ lg, float* __restrict__ ls,
    float* __restrict__ rowm, float* __restrict__ rowd) {
    const int i = blockIdx.x;
    const int t = threadIdx.x;
    const float* HAi = HA + i * 64;
    const float* w1 = ew1 + 128 * 64;
    const float gamma = __expf(lg[0]);
    const float svb0 = svb[0];
    const float xi0 = x[i * 3 + 0], xi1 = x[i * 3 + 1], xi2 = x[i * 3 + 2];

    float4 xa = ((const float4*)x)[3 * t + 0];
    float4 xb = ((const float4*)x)[3 * t + 1];
    float4 xc = ((const float4*)x)[3 * t + 2];
    float nrm[4], le[4], lv[4];
    {
        float dx0 = xi0 - xa.x, dy0 = xi1 - xa.y, dz0 = xi2 - xa.z;
        float dx1 = xi0 - xa.w, dy1 = xi1 - xb.x, dz1 = xi2 - xb.y;
        float dx2 = xi0 - xb.z, dy2 = xi1 - xb.w, dz2 = xi2 - xc.x;
        float dx3 = xi0 - xc.y, dy3 = xi1 - xc.z, dz3 = xi2 - xc.w;
        nrm[0] = pnorm(dx0, dy0, dz0);
        nrm[1] = pnorm(dx1, dy1, dz1);
        nrm[2] = pnorm(dx2, dy2, dz2);
        nrm[3] = pnorm(dx3, dy3, dz3);
    }
    float d0 = 0.f, d1 = 0.f, d2 = 0.f, d3 = 0.f;
#pragma unroll 8
    for (int k = 0; k < 64; k++) {
        float4 hb = *(const float4*)&HBT[k * NN + 4 * t];
        float hk = HAi[k], w1k = w1[k], wv = wsv[k];
        d0 += siluf(hk + hb.x + nrm[0] * w1k) * wv;
        d1 += siluf(hk + hb.y + nrm[1] * w1k) * wv;
        d2 += siluf(hk + hb.z + nrm[2] * w1k) * wv;
        d3 += siluf(hk + hb.w + nrm[3] * w1k) * wv;
    }
    float me = -3.0e38f, ms = -3.0e38f;
    float4 svo;
    {
        float dd[4] = {d0, d1, d2, d3};
#pragma unroll
        for (int m = 0; m < 4; m++) {
            int j = 4 * t + m;
            float sv = dd[m] + svb0;
            sv = sv >= 0.f ? sv : 0.01f * sv;
            if (j == i) sv -= BIGINF;
            lv[m] = sv;
            le[m] = -(nrm[m] + (j == i ? BIGINF : 0.f)) * gamma;
            me = fmaxf(me, le[m]);
            ms = fmaxf(ms, lv[m]);
        }
        svo.x = lv[0]; svo.y = lv[1]; svo.z = lv[2]; svo.w = lv[3];
    }
    *(float4*)&ls[(size_t)i * NN + 4 * t] = svo;

    __shared__ float sm[4], ss[4], s1[4], s2[4], s3[4];
#pragma unroll
    for (int off = 32; off > 0; off >>= 1) {
        me = fmaxf(me, __shfl_xor(me, off, 64));
        ms = fmaxf(ms, __shfl_xor(ms, off, 64));
    }
    const int w = t >> 6;
    if ((t & 63) == 0) { sm[w] = me; ss[w] = ms; }
    __syncthreads();
    me = fmaxf(fmaxf(sm[0], sm[1]), fmaxf(sm[2], sm[3]));
    ms = fmaxf(fmaxf(ss[0], ss[1]), fmaxf(ss[2], ss[3]));
    float Se = 0.f, Ss = 0.f, Sq = 0.f;
#pragma unroll
    for (int m = 0; m < 4; m++) {
        float ee = __expf(le[m] - me);
        float es = __expf(lv[m] - ms);
        Se += ee; Ss += es; Sq += ee * es;
    }
    Se = wsum(Se); Ss = wsum(Ss); Sq = wsum(Sq);
    if ((t & 63) == 0) { s1[w] = Se; s2[w] = Ss; s3[w] = Sq; }
    __syncthreads();
    if (t == 0) {
        rowm[i] = me + ms;
        rowd[i] = (s3[0] + s3[1] + s3[2] + s3[3]) +
                  EPSV * (s1[0] + s1[1] + s1[2] + s1[3]) * (s2[0] + s2[1] + s2[2] + s2[3]);
    }
}

// stage bf16 weight rows into LDS stride-LSTR (512-thread version)
__device__ __forceinline__ void stageW(const short* __restrict__ g, short* s,
                                       int tid, int rows) {
    for (int c = tid; c < rows * 16; c += 512) {
        int r = c >> 4, q = c & 15;
        *(short4v*)&s[r * LSTR + q * 4] = *(const short4v*)&g[r * 64 + q * 4];
    }
}

// ---- kD: one i per block (1024 blocks), 8 j-subtiles looped, no inner barriers ----
__global__ __launch_bounds__(512) void kD(
    const float* __restrict__ x, const float* __restrict__ ew1,
    const float* __restrict__ eb2, const float* __restrict__ cb1,
    const float* __restrict__ cw2, const float* __restrict__ fb1,
    const float* __restrict__ fb2, const float* __restrict__ lg,
    const float* __restrict__ HA, const float* __restrict__ HB,
    const short* __restrict__ ew2T, const short* __restrict__ cw1T,
    const short* __restrict__ fw1T, const short* __restrict__ fw2T,
    const float* __restrict__ ls, const float* __restrict__ rowm,
    const float* __restrict__ rowd, float* __restrict__ hagg,
    float* __restrict__ combos, float* __restrict__ xupd) {
    __shared__ __align__(16) short sWe[64 * LSTR];   // ew2
    __shared__ __align__(16) short sWc[64 * LSTR];   // cw1
    __shared__ __align__(16) short sWf[64 * LSTR];   // fw1
    __shared__ __align__(16) short sW2[32 * LSTR];   // fw2
    __shared__ __align__(16) short sScr[8][16 * LSTR];  // per-wave scratch
    __shared__ float sHag[64], sCombos[96], sXupd[3];

    const int tid = threadIdx.x;
    const int i = blockIdx.x;
    const int lane = tid & 63, w = tid >> 6;       // wave 0..7
    const int col = lane & 15, quad = lane >> 4;

    stageW(ew2T, sWe, tid, 64);
    stageW(cw1T, sWc, tid, 64);
    stageW(fw1T, sWf, tid, 64);
    stageW(fw2T, sW2, tid, 32);
    if (tid < 64) sHag[tid] = 0.f;
    else if (tid < 160) sCombos[tid - 64] = 0.f;
    else if (tid < 163) sXupd[tid - 160] = 0.f;

    short* scr = sScr[w];
    const float gamma = __expf(lg[0]);

    // loop-invariant register fragments / bias vectors
    float w1r[2][8], har[2][8];
#pragma unroll
    for (int kb = 0; kb < 2; kb++)
#pragma unroll
        for (int t = 0; t < 8; t++) {
            w1r[kb][t] = ew1[128 * 64 + kb * 32 + quad * 8 + t];
            har[kb][t] = HA[i * 64 + kb * 32 + quad * 8 + t];
        }
    float eb[4], cbv[4], cwv[4], fbv[4];
#pragma unroll
    for (int nb = 0; nb < 4; nb++) {
        eb[nb] = eb2[nb * 16 + col];
        cbv[nb] = cb1[nb * 16 + col];
        cwv[nb] = cw2[nb * 16 + col];
        fbv[nb] = fb1[nb * 16 + col];
    }
    float fb2v[2] = {fb2[col], fb2[16 + col]};
    const float rm = rowm[i];
    const float invd = 1.0f / rowd[i];
    const float xi0 = x[i * 3 + 0], xi1 = x[i * 3 + 1], xi2 = x[i * 3 + 2];
    const float* lsi = ls + (size_t)i * NN;
    __syncthreads();  // weights staged + accumulators zeroed

#pragma unroll 1
    for (int jt = 0; jt < 8; jt++) {
        const int jrow = jt * JT + w * 16 + col;
        float dxv = xi0 - x[jrow * 3 + 0];
        float dyv = xi1 - x[jrow * 3 + 1];
        float dzv = xi2 - x[jrow * 3 + 2];
        float nrmv = pnorm(dxv, dyv, dzv);
        float inv1 = __builtin_amdgcn_rcpf(nrmv + 1.0f);
        float fxv = dxv * inv1, fyv = dyv * inv1, fzv = dzv * inv1;
        float le = -(nrmv + (jrow == i ? BIGINF : 0.f)) * gamma;
        float combv = __expf(le + lsi[jrow] - rm) * invd;

        // A-frag in registers
        short8 afr[2];
#pragma unroll
        for (int kb = 0; kb < 2; kb++) {
            const float* hb = &HB[jrow * 64 + kb * 32 + quad * 8];
#pragma unroll
            for (int t = 0; t < 8; t++)
                afr[kb][t] = f2bt(siluf(har[kb][t] + hb[t] + nrmv * w1r[kb][t]));
        }
        // GEMM1: he = U@ew2 + eb2
        f32x4 acc[4] = {{0.f, 0.f, 0.f, 0.f}, {0.f, 0.f, 0.f, 0.f},
                        {0.f, 0.f, 0.f, 0.f}, {0.f, 0.f, 0.f, 0.f}};
#pragma unroll
        for (int kb = 0; kb < 2; kb++) {
#pragma unroll
            for (int nb = 0; nb < 4; nb++) {
                short8 b = *(const short8*)&sWe[(nb * 16 + col) * LSTR + kb * 32 + quad * 8];
                acc[nb] = __builtin_amdgcn_mfma_f32_16x16x32_bf16(afr[kb], b, acc[nb], 0, 0, 0);
            }
        }
        // he epilogue: scratch + hagg partial
        {
            float hv[4][4], cmb[4];
#pragma unroll
            for (int reg = 0; reg < 4; reg++) cmb[reg] = __shfl(combv, quad * 4 + reg, 64);
#pragma unroll
            for (int reg = 0; reg < 4; reg++) {
#pragma unroll
                for (int nb = 0; nb < 4; nb++) {
                    hv[nb][reg] = acc[nb][reg] + eb[nb];
                    scr[(quad * 4 + reg) * LSTR + nb * 16 + col] = f2bt(hv[nb][reg]);
                }
            }
#pragma unroll
            for (int nb = 0; nb < 4; nb++) {
                float v = 0.f;
#pragma unroll
                for (int reg = 0; reg < 4; reg++) v += hv[nb][reg] * cmb[reg];
                v = redquad(v);
                if (quad == 0) atomicAdd(&sHag[nb * 16 + col], v);
            }
        }
        short8 a0 = *(const short8*)&scr[col * LSTR + quad * 8];
        short8 a1 = *(const short8*)&scr[col * LSTR + 32 + quad * 8];

        // GEMM2 (phi) + xupd partial
        {
            f32x4 p[4] = {{0.f, 0.f, 0.f, 0.f}, {0.f, 0.f, 0.f, 0.f},
                          {0.f, 0.f, 0.f, 0.f}, {0.f, 0.f, 0.f, 0.f}};
#pragma unroll
            for (int nb = 0; nb < 4; nb++) {
                short8 b0 = *(const short8*)&sWc[(nb * 16 + col) * LSTR + quad * 8];
                short8 b1 = *(const short8*)&sWc[(nb * 16 + col) * LSTR + 32 + quad * 8];
                p[nb] = __builtin_amdgcn_mfma_f32_16x16x32_bf16(a0, b0, p[nb], 0, 0, 0);
                p[nb] = __builtin_amdgcn_mfma_f32_16x16x32_bf16(a1, b1, p[nb], 0, 0, 0);
            }
            float xa0 = 0.f, xa1 = 0.f, xa2 = 0.f;
#pragma unroll
            for (int reg = 0; reg < 4; reg++) {
                float ph = 0.f;
#pragma unroll
                for (int nb = 0; nb < 4; nb++) ph += siluf(p[nb][reg] + cbv[nb]) * cwv[nb];
                ph = red16(ph);
                float tdx = __shfl(dxv, quad * 4 + reg, 64);
                float tdy = __shfl(dyv, quad * 4 + reg, 64);
                float tdz = __shfl(dzv, quad * 4 + reg, 64);
                if (col == 0) { xa0 += ph * tdx; xa1 += ph * tdy; xa2 += ph * tdz; }
            }
            xa0 = wsum(xa0); xa1 = wsum(xa1); xa2 = wsum(xa2);
            if (lane == 0) {
                atomicAdd(&sXupd[0], xa0);
                atomicAdd(&sXupd[1], xa1);
                atomicAdd(&sXupd[2], xa2);
            }
        }

        // GEMM-V: wv = silu(comb*V + fb1) -> scratch
        {
            f32x4 vacc[4] = {{0.f, 0.f, 0.f, 0.f}, {0.f, 0.f, 0.f, 0.f},
                             {0.f, 0.f, 0.f, 0.f}, {0.f, 0.f, 0.f, 0.f}};
#pragma unroll
            for (int nb = 0; nb < 4; nb++) {
                short8 b0 = *(const short8*)&sWf[(nb * 16 + col) * LSTR + quad * 8];
                short8 b1 = *(const short8*)&sWf[(nb * 16 + col) * LSTR + 32 + quad * 8];
                vacc[nb] = __builtin_amdgcn_mfma_f32_16x16x32_bf16(a0, b0, vacc[nb], 0, 0, 0);
                vacc[nb] = __builtin_amdgcn_mfma_f32_16x16x32_bf16(a1, b1, vacc[nb], 0, 0, 0);
            }
            float cmb[4];
#pragma unroll
            for (int reg = 0; reg < 4; reg++) cmb[reg] = __shfl(combv, quad * 4 + reg, 64);
#pragma unroll
            for (int reg = 0; reg < 4; reg++) {
#pragma unroll
                for (int nb = 0; nb < 4; nb++)
                    scr[(quad * 4 + reg) * LSTR + nb * 16 + col] =
                        f2bt(siluf(cmb[reg] * vacc[nb][reg] + fbv[nb]));
            }
        }
        short8 wa0 = *(const short8*)&scr[col * LSTR + quad * 8];
        short8 wa1 = *(const short8*)&scr[col * LSTR + 32 + quad * 8];

        // GEMM-C: coeff = wv@fw2 + fb2 (N=32); combos partial
        {
            f32x4 cacc[2] = {{0.f, 0.f, 0.f, 0.f}, {0.f, 0.f, 0.f, 0.f}};
#pragma unroll
            for (int nb = 0; nb < 2; nb++) {
                short8 b0 = *(const short8*)&sW2[(nb * 16 + col) * LSTR + quad * 8];
                short8 b1 = *(const short8*)&sW2[(nb * 16 + col) * LSTR + 32 + quad * 8];
                cacc[nb] = __builtin_amdgcn_mfma_f32_16x16x32_bf16(wa0, b0, cacc[nb], 0, 0, 0);
                cacc[nb] = __builtin_amdgcn_mfma_f32_16x16x32_bf16(wa1, b1, cacc[nb], 0, 0, 0);
            }
#pragma unroll
            for (int nb = 0; nb < 2; nb++) {
                float px = 0.f, py = 0.f, pz = 0.f;
#pragma unroll
                for (int reg = 0; reg < 4; reg++) {
                    float cf = cacc[nb][reg] + fb2v[nb];
                    float tfx = __shfl(fxv, quad * 4 + reg, 64);
                    float tfy = __shfl(fyv, quad * 4 + reg, 64);
                    float tfz = __shfl(fzv, quad * 4 + reg, 64);
                    px += cf * tfx; py += cf * tfy; pz += cf * tfz;
                }
                px = redquad(px); py = redquad(py); pz = redquad(pz);
                if (quad == 0) {
                    int c = nb * 16 + col;
                    atomicAdd(&sCombos[c * 3 + 0], px);
                    atomicAdd(&sCombos[c * 3 + 1], py);
                    atomicAdd(&sCombos[c * 3 + 2], pz);
                }
            }
        }
    }  // jt
    __syncthreads();  // all waves' LDS atomics done
    // single owner per i -> plain stores
    if (tid < 64) hagg[i * 64 + tid] = sHag[tid];
    else if (tid < 160) combos[i * 96 + tid - 64] = sCombos[tid - 64];
    else if (tid < 163) xupd[i * 3 + tid - 160] = sXupd[tid - 160];
}

// ---- kE: post MLPs + node update + coordinate output (verified) ----
__global__ void kE(const float* __restrict__ h, const float* __restrict__ x,
                   const float* __restrict__ nw1, const float* __restrict__ nb1,
                   const float* __restrict__ nw2, const float* __restrict__ nb2,
                   const float* __restrict__ pw1, const float* __restrict__ pb1,
                   const float* __restrict__ pw2, const float* __restrict__ pb2,
                   const float* __restrict__ hagg, const float* __restrict__ combos,
                   const float* __restrict__ xupd, float* __restrict__ out) {
    const int i = blockIdx.x, o = threadIdx.x;
    const float invN = 1.0f / (float)NN;
    float r = 0.f;
    if (o < 32) {
        float v0 = combos[i * 96 + o * 3 + 0] * invN;
        float v1 = combos[i * 96 + o * 3 + 1] * invN;
        float v2 = combos[i * 96 + o * 3 + 2] * invN;
        r = v0 * v0 + v1 * v1 + v2 * v2;
    }
    float t1 = pb1[o];
#pragma unroll
    for (int k = 0; k < 32; k++) t1 += __shfl(r, k, 64) * pw1[k * 64 + o];
    t1 = siluf(t1);
    float hc = pb2[o];
#pragma unroll
    for (int k = 0; k < 64; k++) hc += __shfl(t1, k, 64) * pw2[k * 64 + o];
    float hi = h[i * 64 + o];
    float ha = hagg[i * 64 + o];
    float t2 = nb1[o];
#pragma unroll
    for (int k = 0; k < 64; k++) t2 += __shfl(hi, k, 64) * nw1[k * 64 + o];
#pragma unroll
    for (int k = 0; k < 64; k++) t2 += __shfl(ha, k, 64) * nw1[(64 + k) * 64 + o];
#pragma unroll
    for (int k = 0; k < 64; k++) t2 += __shfl(hc, k, 64) * nw1[(128 + k) * 64 + o];
    t2 = siluf(t2);
    float ho = hi + nb2[o];
#pragma unroll
    for (int k = 0; k < 64; k++) ho += __shfl(t2, k, 64) * nw2[k * 64 + o];
    out[i * 64 + o] = ho;
    if (o < 3)
        out[NN * 64 + i * 3 + o] = x[i * 3 + o] + xupd[i * 3 + o] * invN;
}

extern "C" void kernel_launch(void* const* d_in, const int* in_sizes, int n_in,
                              void* d_out, int out_size, void* d_ws, size_t ws_size,
                              hipStream_t stream) {
    (void)in_sizes; (void)n_in; (void)out_size; (void)ws_size;
    const float* h   = (const float*)d_in[0];
    const float* x   = (const float*)d_in[1];
    const float* ew1 = (const float*)d_in[2];
    const float* eb1 = (const float*)d_in[3];
    const float* ew2 = (const float*)d_in[4];
    const float* eb2 = (const float*)d_in[5];
    const float* nw1 = (const float*)d_in[6];
    const float* nb1 = (const float*)d_in[7];
    const float* nw2 = (const float*)d_in[8];
    const float* nb2 = (const float*)d_in[9];
    const float* cw1 = (const float*)d_in[10];
    const float* cb1 = (const float*)d_in[11];
    const float* cw2 = (const float*)d_in[12];
    const float* aw  = (const float*)d_in[13];
    const float* ab  = (const float*)d_in[14];
    const float* fw1 = (const float*)d_in[15];
    const float* fb1 = (const float*)d_in[16];
    const float* fw2 = (const float*)d_in[17];
    const float* fb2 = (const float*)d_in[18];
    const float* pw1 = (const float*)d_in[19];
    const float* pb1 = (const float*)d_in[20];
    const float* pw2 = (const float*)d_in[21];
    const float* pb2 = (const float*)d_in[22];
    const float* lg  = (const float*)d_in[23];
    float* out = (float*)d_out;

    float* W      = (float*)d_ws;
    float* ls     = W;                        // N*N
    float* HA     = ls + (size_t)NN * NN;     // N*64
    float* HB     = HA + NN * 64;             // N*64
    float* HBT    = HB + NN * 64;             // 64*N (transposed copy for kBn)
    float* rowm   = HBT + NN * 64;            // N
    float* rowd   = rowm + NN;                // N
    float* hagg   = rowd + NN;                // N*64   (direct store)
    float* combos = hagg + NN * 64;           // N*96   (direct store)
    float* xupd   = combos + NN * 96;         // N*3    (direct store)
    float* wsv    = xupd + NN * 3;            // 64
    float* svb    = wsv + 64;                 // 1
    short* ew2T   = (short*)(svb + 4);        // 64*64 bf16
    short* cw1T   = ew2T + 64 * 64;
    short* fw1T   = cw1T + 64 * 64;
    short* fw2T   = fw1T + 64 * 64;           // 32*64 bf16

    kA<<<NN + 65, 64, 0, stream>>>(h, ew1, eb1, ew2, cw1, fw1, fw2, aw, ab, eb2,
                                   HA, HB, HBT, ew2T, cw1T, fw1T, fw2T, wsv, svb);
    kBn<<<NN, 256, 0, stream>>>(x, ew1, HA, HBT, wsv, svb, lg, ls, rowm, rowd);
    kD<<<NN, 512, 0, stream>>>(x, ew1, eb2, cb1, cw2, fb1, fb2, lg, HA, HB,
                               ew2T, cw1T, fw1T, fw2T, ls, rowm, rowd,
                               hagg, combos, xupd);
    kE<<<NN, 64, 0, stream>>>(h, x, nw1, nb1, nw2, nb2, pw1, pb1, pw2, pb2,
                              hagg, combos, xupd, out);
}

// Round 16
// 279.303 us; speedup vs baseline: 1.0888x; 1.0888x over previous
//
#include <hip/hip_runtime.h>
#include <hip/hip_bf16.h>

#define NN 1024
#define LSTR 72  // bf16 row stride (2-way bank aliasing only — free; 16B-aligned rows)
#define EPSV 1e-5f
#define BIGINF 1e5f

typedef __attribute__((ext_vector_type(8))) short short8;
typedef __attribute__((ext_vector_type(4))) short short4v;
typedef __attribute__((ext_vector_type(4))) float f32x4;

__device__ __forceinline__ float siluf(float v) {
    return v * __builtin_amdgcn_rcpf(1.0f + __expf(-v));
}
__device__ __forceinline__ float pnorm(float dx, float dy, float dz) {
    return sqrtf(dx * dx + dy * dy + dz * dz + EPSV);
}
__device__ __forceinline__ float wsum(float v) {
#pragma unroll
    for (int off = 32; off > 0; off >>= 1) v += __shfl_xor(v, off, 64);
    return v;
}
__device__ __forceinline__ float red16(float v) {
    v += __shfl_xor(v, 1, 64); v += __shfl_xor(v, 2, 64);
    v += __shfl_xor(v, 4, 64); v += __shfl_xor(v, 8, 64);
    return v;
}
__device__ __forceinline__ float redquad(float v) {
    v += __shfl_xor(v, 16, 64); v += __shfl_xor(v, 32, 64);
    return v;
}
__device__ __forceinline__ short f2bs(float v) {  // RNE (weights, once)
    __hip_bfloat16 b = __float2bfloat16(v);
    return *reinterpret_cast<short*>(&b);
}
__device__ __forceinline__ short f2bt(float v) {  // truncate (hot path)
    return (short)(__float_as_uint(v) >> 16);
}

// ---- kA (fused): [0,NN): HA/HB/HBT; [NN,NN+64): weight transposes; NN+64: wsv/svb ----
__global__ void kA(const float* __restrict__ h, const float* __restrict__ ew1,
                   const float* __restrict__ eb1, const float* __restrict__ ew2,
                   const float* __restrict__ cw1, const float* __restrict__ fw1,
                   const float* __restrict__ fw2, const float* __restrict__ aw,
                   const float* __restrict__ ab, const float* __restrict__ eb2,
                   float* __restrict__ HA, float* __restrict__ HB,
                   float* __restrict__ HBT, short* __restrict__ ew2T,
                   short* __restrict__ cw1T, short* __restrict__ fw1T,
                   short* __restrict__ fw2T, float* __restrict__ wsv,
                   float* __restrict__ svb) {
    const int b = blockIdx.x;
    const int o = threadIdx.x;
    if (b < NN) {
        const int i = b;
        float hv = h[i * 64 + o];
        float a = 0.f, bb = eb1[o];
#pragma unroll
        for (int k = 0; k < 64; k++) {
            float hk = __shfl(hv, k, 64);
            a += hk * ew1[k * 64 + o];
            bb += hk * ew1[(64 + k) * 64 + o];
        }
        HA[i * 64 + o] = a;
        HB[i * 64 + o] = bb;
        HBT[o * NN + i] = bb;
    } else if (b < NN + 64) {
        const int r = b - NN;
        ew2T[r * 64 + o] = f2bs(ew2[o * 64 + r]);
        cw1T[r * 64 + o] = f2bs(cw1[o * 64 + r]);
        fw1T[r * 64 + o] = f2bs(fw1[o * 64 + r]);
        if (r < 32) fw2T[r * 64 + o] = f2bs(fw2[o * 32 + r]);
    } else {
        float s = 0.f;
#pragma unroll
        for (int q = 0; q < 64; q++) s += ew2[o * 64 + q] * aw[q];
        wsv[o] = s;
        float e = wsum(eb2[o] * aw[o]);
        if (o == 0) svb[0] = e + ab[0];
    }
}

// ---- kBn: pass 1 — thread t handles j=4t..4t+3, coalesced HBT float4 loads ----
__global__ __launch_bounds__(256) void kBn(
    const float* __restrict__ x, const float* __restrict__ ew1,
    const float* __restrict__ HA, const float* __restrict__ HBT,
    const float* __restrict__ wsv, const float* __restrict__ svb,
    const float* __restrict__ lg, float* __restrict__ ls,
    float* __restrict__ rowm, float* __restrict__ rowd) {
    const int i = blockIdx.x;
    const int t = threadIdx.x;
    const float* HAi = HA + i * 64;
    const float* w1 = ew1 + 128 * 64;
    const float gamma = __expf(lg[0]);
    const float svb0 = svb[0];
    const float xi0 = x[i * 3 + 0], xi1 = x[i * 3 + 1], xi2 = x[i * 3 + 2];

    float4 xa = ((const float4*)x)[3 * t + 0];
    float4 xb = ((const float4*)x)[3 * t + 1];
    float4 xc = ((const float4*)x)[3 * t + 2];
    float nrm[4], le[4], lv[4];
    {
        float dx0 = xi0 - xa.x, dy0 = xi1 - xa.y, dz0 = xi2 - xa.z;
        float dx1 = xi0 - xa.w, dy1 = xi1 - xb.x, dz1 = xi2 - xb.y;
        float dx2 = xi0 - xb.z, dy2 = xi1 - xb.w, dz2 = xi2 - xc.x;
        float dx3 = xi0 - xc.y, dy3 = xi1 - xc.z, dz3 = xi2 - xc.w;
        nrm[0] = pnorm(dx0, dy0, dz0);
        nrm[1] = pnorm(dx1, dy1, dz1);
        nrm[2] = pnorm(dx2, dy2, dz2);
        nrm[3] = pnorm(dx3, dy3, dz3);
    }
    float d0 = 0.f, d1 = 0.f, d2 = 0.f, d3 = 0.f;
#pragma unroll 8
    for (int k = 0; k < 64; k++) {
        float4 hb = *(const float4*)&HBT[k * NN + 4 * t];
        float hk = HAi[k], w1k = w1[k], wv = wsv[k];
        d0 += siluf(hk + hb.x + nrm[0] * w1k) * wv;
        d1 += siluf(hk + hb.y + nrm[1] * w1k) * wv;
        d2 += siluf(hk + hb.z + nrm[2] * w1k) * wv;
        d3 += siluf(hk + hb.w + nrm[3] * w1k) * wv;
    }
    float me = -3.0e38f, ms = -3.0e38f;
    float4 svo;
    {
        float dd[4] = {d0, d1, d2, d3};
#pragma unroll
        for (int m = 0; m < 4; m++) {
            int j = 4 * t + m;
            float sv = dd[m] + svb0;
            sv = sv >= 0.f ? sv : 0.01f * sv;
            if (j == i) sv -= BIGINF;
            lv[m] = sv;
            le[m] = -(nrm[m] + (j == i ? BIGINF : 0.f)) * gamma;
            me = fmaxf(me, le[m]);
            ms = fmaxf(ms, lv[m]);
        }
        svo.x = lv[0]; svo.y = lv[1]; svo.z = lv[2]; svo.w = lv[3];
    }
    *(float4*)&ls[(size_t)i * NN + 4 * t] = svo;

    __shared__ float sm[4], ss[4], s1[4], s2[4], s3[4];
#pragma unroll
    for (int off = 32; off > 0; off >>= 1) {
        me = fmaxf(me, __shfl_xor(me, off, 64));
        ms = fmaxf(ms, __shfl_xor(ms, off, 64));
    }
    const int w = t >> 6;
    if ((t & 63) == 0) { sm[w] = me; ss[w] = ms; }
    __syncthreads();
    me = fmaxf(fmaxf(sm[0], sm[1]), fmaxf(sm[2], sm[3]));
    ms = fmaxf(fmaxf(ss[0], ss[1]), fmaxf(ss[2], ss[3]));
    float Se = 0.f, Ss = 0.f, Sq = 0.f;
#pragma unroll
    for (int m = 0; m < 4; m++) {
        float ee = __expf(le[m] - me);
        float es = __expf(lv[m] - ms);
        Se += ee; Ss += es; Sq += ee * es;
    }
    Se = wsum(Se); Ss = wsum(Ss); Sq = wsum(Sq);
    if ((t & 63) == 0) { s1[w] = Se; s2[w] = Ss; s3[w] = Sq; }
    __syncthreads();
    if (t == 0) {
        rowm[i] = me + ms;
        rowd[i] = (s3[0] + s3[1] + s3[2] + s3[3]) +
                  EPSV * (s1[0] + s1[1] + s1[2] + s1[3]) * (s2[0] + s2[1] + s2[2] + s2[3]);
    }
}

// stage bf16 weight rows into LDS stride-LSTR (512-thread version)
__device__ __forceinline__ void stageW(const short* __restrict__ g, short* s,
                                       int tid, int rows) {
    for (int c = tid; c < rows * 16; c += 512) {
        int r = c >> 4, q = c & 15;
        *(short4v*)&s[r * LSTR + q * 4] = *(const short4v*)&g[r * 64 + q * 4];
    }
}

// ---- kD: one i per block, 4 j-subtiles of 256, 2 rows per wave (ILP x2) ----
__global__ __launch_bounds__(512) void kD(
    const float* __restrict__ x, const float* __restrict__ ew1,
    const float* __restrict__ eb2, const float* __restrict__ cb1,
    const float* __restrict__ cw2, const float* __restrict__ fb1,
    const float* __restrict__ fb2, const float* __restrict__ lg,
    const float* __restrict__ HA, const float* __restrict__ HB,
    const short* __restrict__ ew2T, const short* __restrict__ cw1T,
    const short* __restrict__ fw1T, const short* __restrict__ fw2T,
    const float* __restrict__ ls, const float* __restrict__ rowm,
    const float* __restrict__ rowd, float* __restrict__ hagg,
    float* __restrict__ combos, float* __restrict__ xupd) {
    __shared__ __align__(16) short sWe[64 * LSTR];   // ew2
    __shared__ __align__(16) short sWf[64 * LSTR];   // fw1
    __shared__ __align__(16) short sW2[32 * LSTR];   // fw2
    __shared__ __align__(16) short sScr[16][16 * LSTR];  // 2 per wave
    __shared__ float sHag[64], sCombos[96], sXupd[3];

    const int tid = threadIdx.x;
    const int i = blockIdx.x;
    const int lane = tid & 63, w = tid >> 6;       // wave 0..7
    const int col = lane & 15, quad = lane >> 4;

    stageW(ew2T, sWe, tid, 64);
    stageW(fw1T, sWf, tid, 64);
    stageW(fw2T, sW2, tid, 32);
    if (tid < 64) sHag[tid] = 0.f;
    else if (tid < 160) sCombos[tid - 64] = 0.f;
    else if (tid < 163) sXupd[tid - 160] = 0.f;

    short* scr0 = sScr[2 * w];
    short* scr1 = sScr[2 * w + 1];
    const float gamma = __expf(lg[0]);

    // loop-invariant register fragments / bias vectors
    float w1r[2][8], har[2][8];
#pragma unroll
    for (int kb = 0; kb < 2; kb++)
#pragma unroll
        for (int t = 0; t < 8; t++) {
            w1r[kb][t] = ew1[128 * 64 + kb * 32 + quad * 8 + t];
            har[kb][t] = HA[i * 64 + kb * 32 + quad * 8 + t];
        }
    float eb[4], cbv[4], cwv[4], fbv[4];
#pragma unroll
    for (int nb = 0; nb < 4; nb++) {
        eb[nb] = eb2[nb * 16 + col];
        cbv[nb] = cb1[nb * 16 + col];
        cwv[nb] = cw2[nb * 16 + col];
        fbv[nb] = fb1[nb * 16 + col];
    }
    float fb2v[2] = {fb2[col], fb2[16 + col]};
    const float rm = rowm[i];
    const float invd = 1.0f / rowd[i];
    const float xi0 = x[i * 3 + 0], xi1 = x[i * 3 + 1], xi2 = x[i * 3 + 2];
    const float* lsi = ls + (size_t)i * NN;
    __syncthreads();  // weights staged + accumulators zeroed

#pragma unroll 1
    for (int jt = 0; jt < 4; jt++) {
        const int r0 = jt * 256 + w * 16 + col;
        const int r1 = r0 + 128;
        // geometry, both rows
        float dx0 = xi0 - x[r0 * 3 + 0], dy0 = xi1 - x[r0 * 3 + 1], dz0 = xi2 - x[r0 * 3 + 2];
        float dx1 = xi0 - x[r1 * 3 + 0], dy1 = xi1 - x[r1 * 3 + 1], dz1 = xi2 - x[r1 * 3 + 2];
        float nr0 = pnorm(dx0, dy0, dz0), nr1 = pnorm(dx1, dy1, dz1);
        float iv0 = __builtin_amdgcn_rcpf(nr0 + 1.0f), iv1 = __builtin_amdgcn_rcpf(nr1 + 1.0f);
        float fx0 = dx0 * iv0, fy0 = dy0 * iv0, fz0 = dz0 * iv0;
        float fx1 = dx1 * iv1, fy1 = dy1 * iv1, fz1 = dz1 * iv1;
        float le0 = -(nr0 + (r0 == i ? BIGINF : 0.f)) * gamma;
        float le1 = -(nr1 + (r1 == i ? BIGINF : 0.f)) * gamma;
        float cb0 = __expf(le0 + lsi[r0] - rm) * invd;
        float cb1f = __expf(le1 + lsi[r1] - rm) * invd;

        // A-frags, both rows
        short8 af0[2], af1[2];
#pragma unroll
        for (int kb = 0; kb < 2; kb++) {
            const float* hb0 = &HB[r0 * 64 + kb * 32 + quad * 8];
            const float* hb1 = &HB[r1 * 64 + kb * 32 + quad * 8];
#pragma unroll
            for (int t = 0; t < 8; t++) {
                af0[kb][t] = f2bt(siluf(har[kb][t] + hb0[t] + nr0 * w1r[kb][t]));
                af1[kb][t] = f2bt(siluf(har[kb][t] + hb1[t] + nr1 * w1r[kb][t]));
            }
        }
        // GEMM1 x2: he = U@ew2 + eb2 (B shared)
        f32x4 ac0[4] = {{0.f,0.f,0.f,0.f},{0.f,0.f,0.f,0.f},{0.f,0.f,0.f,0.f},{0.f,0.f,0.f,0.f}};
        f32x4 ac1[4] = {{0.f,0.f,0.f,0.f},{0.f,0.f,0.f,0.f},{0.f,0.f,0.f,0.f},{0.f,0.f,0.f,0.f}};
#pragma unroll
        for (int kb = 0; kb < 2; kb++) {
#pragma unroll
            for (int nb = 0; nb < 4; nb++) {
                short8 b = *(const short8*)&sWe[(nb * 16 + col) * LSTR + kb * 32 + quad * 8];
                ac0[nb] = __builtin_amdgcn_mfma_f32_16x16x32_bf16(af0[kb], b, ac0[nb], 0, 0, 0);
                ac1[nb] = __builtin_amdgcn_mfma_f32_16x16x32_bf16(af1[kb], b, ac1[nb], 0, 0, 0);
            }
        }
        // he epilogue: scratch x2 + hagg partial (both rows folded)
        {
            float cm0[4], cm1[4];
#pragma unroll
            for (int reg = 0; reg < 4; reg++) {
                cm0[reg] = __shfl(cb0, quad * 4 + reg, 64);
                cm1[reg] = __shfl(cb1f, quad * 4 + reg, 64);
            }
#pragma unroll
            for (int nb = 0; nb < 4; nb++) {
                float v = 0.f;
#pragma unroll
                for (int reg = 0; reg < 4; reg++) {
                    float h0 = ac0[nb][reg] + eb[nb];
                    float h1 = ac1[nb][reg] + eb[nb];
                    scr0[(quad * 4 + reg) * LSTR + nb * 16 + col] = f2bt(h0);
                    scr1[(quad * 4 + reg) * LSTR + nb * 16 + col] = f2bt(h1);
                    v += h0 * cm0[reg] + h1 * cm1[reg];
                }
                v = redquad(v);
                if (quad == 0) atomicAdd(&sHag[nb * 16 + col], v);
            }
        }
        short8 a00 = *(const short8*)&scr0[col * LSTR + quad * 8];
        short8 a01 = *(const short8*)&scr0[col * LSTR + 32 + quad * 8];
        short8 a10 = *(const short8*)&scr1[col * LSTR + quad * 8];
        short8 a11 = *(const short8*)&scr1[col * LSTR + 32 + quad * 8];

        // GEMM2 (phi) x2 — cw1 B-frags from GLOBAL (L2-hot) — + xupd partial
        {
            f32x4 p0[4] = {{0.f,0.f,0.f,0.f},{0.f,0.f,0.f,0.f},{0.f,0.f,0.f,0.f},{0.f,0.f,0.f,0.f}};
            f32x4 p1[4] = {{0.f,0.f,0.f,0.f},{0.f,0.f,0.f,0.f},{0.f,0.f,0.f,0.f},{0.f,0.f,0.f,0.f}};
#pragma unroll
            for (int nb = 0; nb < 4; nb++) {
                short8 b0 = *(const short8*)&cw1T[(nb * 16 + col) * 64 + quad * 8];
                short8 b1 = *(const short8*)&cw1T[(nb * 16 + col) * 64 + 32 + quad * 8];
                p0[nb] = __builtin_amdgcn_mfma_f32_16x16x32_bf16(a00, b0, p0[nb], 0, 0, 0);
                p0[nb] = __builtin_amdgcn_mfma_f32_16x16x32_bf16(a01, b1, p0[nb], 0, 0, 0);
                p1[nb] = __builtin_amdgcn_mfma_f32_16x16x32_bf16(a10, b0, p1[nb], 0, 0, 0);
                p1[nb] = __builtin_amdgcn_mfma_f32_16x16x32_bf16(a11, b1, p1[nb], 0, 0, 0);
            }
            float xa0 = 0.f, xa1 = 0.f, xa2 = 0.f;
#pragma unroll
            for (int reg = 0; reg < 4; reg++) {
                float ph0 = 0.f, ph1 = 0.f;
#pragma unroll
                for (int nb = 0; nb < 4; nb++) {
                    ph0 += siluf(p0[nb][reg] + cbv[nb]) * cwv[nb];
                    ph1 += siluf(p1[nb][reg] + cbv[nb]) * cwv[nb];
                }
                ph0 = red16(ph0); ph1 = red16(ph1);
                float t0x = __shfl(dx0, quad * 4 + reg, 64);
                float t0y = __shfl(dy0, quad * 4 + reg, 64);
                float t0z = __shfl(dz0, quad * 4 + reg, 64);
                float t1x = __shfl(dx1, quad * 4 + reg, 64);
                float t1y = __shfl(dy1, quad * 4 + reg, 64);
                float t1z = __shfl(dz1, quad * 4 + reg, 64);
                if (col == 0) {
                    xa0 += ph0 * t0x + ph1 * t1x;
                    xa1 += ph0 * t0y + ph1 * t1y;
                    xa2 += ph0 * t0z + ph1 * t1z;
                }
            }
            xa0 = wsum(xa0); xa1 = wsum(xa1); xa2 = wsum(xa2);
            if (lane == 0) {
                atomicAdd(&sXupd[0], xa0);
                atomicAdd(&sXupd[1], xa1);
                atomicAdd(&sXupd[2], xa2);
            }
        }

        // GEMM-V x2: wv = silu(comb*V + fb1) -> scratch x2
        {
            f32x4 v0[4] = {{0.f,0.f,0.f,0.f},{0.f,0.f,0.f,0.f},{0.f,0.f,0.f,0.f},{0.f,0.f,0.f,0.f}};
            f32x4 v1[4] = {{0.f,0.f,0.f,0.f},{0.f,0.f,0.f,0.f},{0.f,0.f,0.f,0.f},{0.f,0.f,0.f,0.f}};
#pragma unroll
            for (int nb = 0; nb < 4; nb++) {
                short8 b0 = *(const short8*)&sWf[(nb * 16 + col) * LSTR + quad * 8];
                short8 b1 = *(const short8*)&sWf[(nb * 16 + col) * LSTR + 32 + quad * 8];
                v0[nb] = __builtin_amdgcn_mfma_f32_16x16x32_bf16(a00, b0, v0[nb], 0, 0, 0);
                v0[nb] = __builtin_amdgcn_mfma_f32_16x16x32_bf16(a01, b1, v0[nb], 0, 0, 0);
                v1[nb] = __builtin_amdgcn_mfma_f32_16x16x32_bf16(a10, b0, v1[nb], 0, 0, 0);
                v1[nb] = __builtin_amdgcn_mfma_f32_16x16x32_bf16(a11, b1, v1[nb], 0, 0, 0);
            }
            float cm0[4], cm1[4];
#pragma unroll
            for (int reg = 0; reg < 4; reg++) {
                cm0[reg] = __shfl(cb0, quad * 4 + reg, 64);
                cm1[reg] = __shfl(cb1f, quad * 4 + reg, 64);
            }
#pragma unroll
            for (int reg = 0; reg < 4; reg++) {
#pragma unroll
                for (int nb = 0; nb < 4; nb++) {
                    scr0[(quad * 4 + reg) * LSTR + nb * 16 + col] =
                        f2bt(siluf(cm0[reg] * v0[nb][reg] + fbv[nb]));
                    scr1[(quad * 4 + reg) * LSTR + nb * 16 + col] =
                        f2bt(siluf(cm1[reg] * v1[nb][reg] + fbv[nb]));
                }
            }
        }
        short8 wa00 = *(const short8*)&scr0[col * LSTR + quad * 8];
        short8 wa01 = *(const short8*)&scr0[col * LSTR + 32 + quad * 8];
        short8 wa10 = *(const short8*)&scr1[col * LSTR + quad * 8];
        short8 wa11 = *(const short8*)&scr1[col * LSTR + 32 + quad * 8];

        // GEMM-C x2: coeff = wv@fw2 + fb2 (N=32); combos partial (both rows folded)
        {
            f32x4 c0[2] = {{0.f,0.f,0.f,0.f},{0.f,0.f,0.f,0.f}};
            f32x4 c1[2] = {{0.f,0.f,0.f,0.f},{0.f,0.f,0.f,0.f}};
#pragma unroll
            for (int nb = 0; nb < 2; nb++) {
                short8 b0 = *(const short8*)&sW2[(nb * 16 + col) * LSTR + quad * 8];
                short8 b1 = *(const short8*)&sW2[(nb * 16 + col) * LSTR + 32 + quad * 8];
                c0[nb] = __builtin_amdgcn_mfma_f32_16x16x32_bf16(wa00, b0, c0[nb], 0, 0, 0);
                c0[nb] = __builtin_amdgcn_mfma_f32_16x16x32_bf16(wa01, b1, c0[nb], 0, 0, 0);
                c1[nb] = __builtin_amdgcn_mfma_f32_16x16x32_bf16(wa10, b0, c1[nb], 0, 0, 0);
                c1[nb] = __builtin_amdgcn_mfma_f32_16x16x32_bf16(wa11, b1, c1[nb], 0, 0, 0);
            }
#pragma unroll
            for (int nb = 0; nb < 2; nb++) {
                float px = 0.f, py = 0.f, pz = 0.f;
#pragma unroll
                for (int reg = 0; reg < 4; reg++) {
                    float cf0 = c0[nb][reg] + fb2v[nb];
                    float cf1 = c1[nb][reg] + fb2v[nb];
                    float t0x = __shfl(fx0, quad * 4 + reg, 64);
                    float t0y = __shfl(fy0, quad * 4 + reg, 64);
                    float t0z = __shfl(fz0, quad * 4 + reg, 64);
                    float t1x = __shfl(fx1, quad * 4 + reg, 64);
                    float t1y = __shfl(fy1, quad * 4 + reg, 64);
                    float t1z = __shfl(fz1, quad * 4 + reg, 64);
                    px += cf0 * t0x + cf1 * t1x;
                    py += cf0 * t0y + cf1 * t1y;
                    pz += cf0 * t0z + cf1 * t1z;
                }
                px = redquad(px); py = redquad(py); pz = redquad(pz);
                if (quad == 0) {
                    int c = nb * 16 + col;
                    atomicAdd(&sCombos[c * 3 + 0], px);
                    atomicAdd(&sCombos[c * 3 + 1], py);
                    atomicAdd(&sCombos[c * 3 + 2], pz);
                }
            }
        }
    }  // jt
    __syncthreads();  // all waves' LDS atomics done
    if (tid < 64) hagg[i * 64 + tid] = sHag[tid];
    else if (tid < 160) combos[i * 96 + tid - 64] = sCombos[tid - 64];
    else if (tid < 163) xupd[i * 3 + tid - 160] = sXupd[tid - 160];
}

// ---- kE: post MLPs + node update + coordinate output (verified) ----
__global__ void kE(const float* __restrict__ h, const float* __restrict__ x,
                   const float* __restrict__ nw1, const float* __restrict__ nb1,
                   const float* __restrict__ nw2, const float* __restrict__ nb2,
                   const float* __restrict__ pw1, const float* __restrict__ pb1,
                   const float* __restrict__ pw2, const float* __restrict__ pb2,
                   const float* __restrict__ hagg, const float* __restrict__ combos,
                   const float* __restrict__ xupd, float* __restrict__ out) {
    const int i = blockIdx.x, o = threadIdx.x;
    const float invN = 1.0f / (float)NN;
    float r = 0.f;
    if (o < 32) {
        float v0 = combos[i * 96 + o * 3 + 0] * invN;
        float v1 = combos[i * 96 + o * 3 + 1] * invN;
        float v2 = combos[i * 96 + o * 3 + 2] * invN;
        r = v0 * v0 + v1 * v1 + v2 * v2;
    }
    float t1 = pb1[o];
#pragma unroll
    for (int k = 0; k < 32; k++) t1 += __shfl(r, k, 64) * pw1[k * 64 + o];
    t1 = siluf(t1);
    float hc = pb2[o];
#pragma unroll
    for (int k = 0; k < 64; k++) hc += __shfl(t1, k, 64) * pw2[k * 64 + o];
    float hi = h[i * 64 + o];
    float ha = hagg[i * 64 + o];
    float t2 = nb1[o];
#pragma unroll
    for (int k = 0; k < 64; k++) t2 += __shfl(hi, k, 64) * nw1[k * 64 + o];
#pragma unroll
    for (int k = 0; k < 64; k++) t2 += __shfl(ha, k, 64) * nw1[(64 + k) * 64 + o];
#pragma unroll
    for (int k = 0; k < 64; k++) t2 += __shfl(hc, k, 64) * nw1[(128 + k) * 64 + o];
    t2 = siluf(t2);
    float ho = hi + nb2[o];
#pragma unroll
    for (int k = 0; k < 64; k++) ho += __shfl(t2, k, 64) * nw2[k * 64 + o];
    out[i * 64 + o] = ho;
    if (o < 3)
        out[NN * 64 + i * 3 + o] = x[i * 3 + o] + xupd[i * 3 + o] * invN;
}

extern "C" void kernel_launch(void* const* d_in, const int* in_sizes, int n_in,
                              void* d_out, int out_size, void* d_ws, size_t ws_size,
                              hipStream_t stream) {
    (void)in_sizes; (void)n_in; (void)out_size; (void)ws_size;
    const float* h   = (const float*)d_in[0];
    const float* x   = (const float*)d_in[1];
    const float* ew1 = (const float*)d_in[2];
    const float* eb1 = (const float*)d_in[3];
    const float* ew2 = (const float*)d_in[4];
    const float* eb2 = (const float*)d_in[5];
    const float* nw1 = (const float*)d_in[6];
    const float* nb1 = (const float*)d_in[7];
    const float* nw2 = (const float*)d_in[8];
    const float* nb2 = (const float*)d_in[9];
    const float* cw1 = (const float*)d_in[10];
    const float* cb1 = (const float*)d_in[11];
    const float* cw2 = (const float*)d_in[12];
    const float* aw  = (const float*)d_in[13];
    const float* ab  = (const float*)d_in[14];
    const float* fw1 = (const float*)d_in[15];
    const float* fb1 = (const float*)d_in[16];
    const float* fw2 = (const float*)d_in[17];
    const float* fb2 = (const float*)d_in[18];
    const float* pw1 = (const float*)d_in[19];
    const float* pb1 = (const float*)d_in[20];
    const float* pw2 = (const float*)d_in[21];
    const float* pb2 = (const float*)d_in[22];
    const float* lg  = (const float*)d_in[23];
    float* out = (float*)d_out;

    float* W      = (float*)d_ws;
    float* ls     = W;                        // N*N
    float* HA     = ls + (size_t)NN * NN;     // N*64
    float* HB     = HA + NN * 64;             // N*64
    float* HBT    = HB + NN * 64;             // 64*N
    float* rowm   = HBT + NN * 64;            // N
    float* rowd   = rowm + NN;                // N
    float* hagg   = rowd + NN;                // N*64   (direct store)
    float* combos = hagg + NN * 64;           // N*96   (direct store)
    float* xupd   = combos + NN * 96;         // N*3    (direct store)
    float* wsv    = xupd + NN * 3;            // 64
    float* svb    = wsv + 64;                 // 1
    short* ew2T   = (short*)(svb + 4);        // 64*64 bf16
    short* cw1T   = ew2T + 64 * 64;
    short* fw1T   = cw1T + 64 * 64;
    short* fw2T   = fw1T + 64 * 64;           // 32*64 bf16

    kA<<<NN + 65, 64, 0, stream>>>(h, ew1, eb1, ew2, cw1, fw1, fw2, aw, ab, eb2,
                                   HA, HB, HBT, ew2T, cw1T, fw1T, fw2T, wsv, svb);
    kBn<<<NN, 256, 0, stream>>>(x, ew1, HA, HBT, wsv, svb, lg, ls, rowm, rowd);
    kD<<<NN, 512, 0, stream>>>(x, ew1, eb2, cb1, cw2, fb1, fb2, lg, HA, HB,
                               ew2T, cw1T, fw1T, fw2T, ls, rowm, rowd,
                               hagg, combos, xupd);
    kE<<<NN, 64, 0, stream>>>(h, x, nw1, nb1, nw2, nb2, pw1, pb1, pw2, pb2,
                              hagg, combos, xupd, out);
}